// Round 8
// baseline (716.927 us; speedup 1.0000x reference)
//
#include <hip/hip_runtime.h>

#define BATCH 4
#define SEQ   2048
#define DIM   2048
#define NH    16
#define HD    128

typedef __bf16 bf16x8 __attribute__((ext_vector_type(8)));
typedef float  f32x4  __attribute__((ext_vector_type(4)));

__device__ __forceinline__ unsigned short f2bf(float f) {
  unsigned int u = __builtin_bit_cast(unsigned int, f);
  u += 0x7fffu + ((u >> 16) & 1u);          // RNE
  return (unsigned short)(u >> 16);
}

// async global->LDS, 16B per lane; LDS dest must be wave-uniform-base + lane*16
__device__ __forceinline__ void async16(void* lds, const void* g) {
  __builtin_amdgcn_global_load_lds(
      (const __attribute__((address_space(1))) unsigned int*)g,
      (__attribute__((address_space(3))) unsigned int*)lds, 16, 0, 0);
}

// ---------------------------------------------------------------- one cast dispatch for x + all 4 weights
__global__ __launch_bounds__(256) void cast_all_kernel(
    const float* __restrict__ x,
    const float* __restrict__ w0, const float* __restrict__ w1,
    const float* __restrict__ w2, const float* __restrict__ w3,
    unsigned short* __restrict__ dst) {
  int i = blockIdx.x * 256 + threadIdx.x;
  const float* s;
  int loc;
  if (i < (1 << 22)) { s = x; loc = i; }
  else {
    int k = i - (1 << 22);
    int sel = k >> 20; loc = k & 0xfffff;
    s = sel == 0 ? w0 : sel == 1 ? w1 : sel == 2 ? w2 : w3;
  }
  float4 v = ((const float4*)s)[loc];
  ushort4 o;
  o.x = f2bf(v.x); o.y = f2bf(v.y); o.z = f2bf(v.z); o.w = f2bf(v.w);
  ((ushort4*)dst)[i] = o;
}

// ---------------------------------------------------------------- fused QKV GEMM + RoPE + V-transpose
// R8: RoPE epilogue dedup — old code computed each sincos TWICE (threads at
// oc and oc^64 share the angle, freq idx = oc&63). Now one thread owns a
// row x 8-col group of the LOWER half, computes one sincos per (c,j), and
// emits BOTH halves (lower = t1*c - t2*s, upper = t2*c + t1*s). Trig evals
// 64 -> 32 per thread; outputs bit-identical. VALUBusy 56% > MfmaUtil 32%
// said VALU-contended; trig is the hog (quarter-rate transcendentals).
// R7 lesson kept: LDS aliasing (ep over As+Bs) was occupancy-neutral but
// harmless; occupancy metric does not respond to static limits here.
__global__ __launch_bounds__(256) void gemm_qkv(
    const unsigned short* __restrict__ A,    // xb (8192 x 2048) bf16
    const unsigned short* __restrict__ Wq,
    const unsigned short* __restrict__ Wk,
    const unsigned short* __restrict__ Wv,
    unsigned short* __restrict__ Qo,
    unsigned short* __restrict__ Ko,
    unsigned short* __restrict__ Vto) {
  __shared__ __align__(16) char smu[32 * 132 * 4];   // 16,896 B: max(As+Bs, ep)
  unsigned short* As = (unsigned short*)smu;          // [128*32] = 8192 B
  unsigned short* Bs = (unsigned short*)(smu + 8192); // [128*32] = 8192 B
  float* ep = (float*)smu;                            // [32*132] = 16896 B (epilogue only)
  const int tid = threadIdx.x;
  const int lane = tid & 63, wv = tid >> 6;
  const int q15 = lane & 15, quad = lane >> 4;
  const int wm = wv >> 1, wn = wv & 1;
  const int gx = blockIdx.x;
  const int sel = gx >> 4, h = gx & 15;
  const int m0 = blockIdx.y * 128;
  const unsigned short* Bw =
      (sel == 0 ? Wq : (sel == 1 ? Wk : Wv)) + (size_t)h * 128 * DIM;

  f32x4 acc[4][4] = {};

  for (int kt = 0; kt < DIM; kt += 32) {
    __syncthreads();
#pragma unroll
    for (int i = 0; i < 2; ++i) {
      int l = i * 256 + tid;
      int r = l >> 2, s = l & 3;
      int c = (s - (r >> 1)) & 3;
      async16(&As[l * 8], A + (size_t)(m0 + r) * DIM + kt + c * 8);
    }
#pragma unroll
    for (int i = 0; i < 2; ++i) {
      int l = i * 256 + tid;
      int r = l >> 2, s = l & 3;
      int c = (s - (r >> 1)) & 3;
      async16(&Bs[l * 8], Bw + (size_t)r * DIM + kt + c * 8);
    }
    __syncthreads();

    bf16x8 af[4], bf[4];
#pragma unroll
    for (int mf = 0; mf < 4; ++mf) {
      int r = wm * 64 + mf * 16 + q15;
      int sl = r * 4 + ((quad + (r >> 1)) & 3);
      af[mf] = *(const bf16x8*)&As[sl * 8];
    }
#pragma unroll
    for (int nf = 0; nf < 4; ++nf) {
      int r = wn * 64 + nf * 16 + q15;
      int sl = r * 4 + ((quad + (r >> 1)) & 3);
      bf[nf] = *(const bf16x8*)&Bs[sl * 8];
    }
#pragma unroll
    for (int mf = 0; mf < 4; ++mf)
#pragma unroll
      for (int nf = 0; nf < 4; ++nf)
        acc[mf][nf] = __builtin_amdgcn_mfma_f32_16x16x32_bf16(af[mf], bf[nf], acc[mf][nf], 0, 0, 0);
  }

  const int b = m0 >> 11;
  const int s0 = m0 & (SEQ - 1);
  const int bh = b * NH + h;
  const float CS = 0.12751744f;   // log2(e)/sqrt(HD), folded into Q

  // one freq set per thread (freq idx = column mod 64 — shared by both halves)
  float invf[8];
  const int rr = tid >> 3, ocg = (tid & 7) * 8;
  if (sel < 2) {
#pragma unroll
    for (int j = 0; j < 8; ++j)
      invf[j] = exp2f(-(float)(ocg + j) * 0.20762050593046932f);
  }

  for (int c = 0; c < 4; ++c) {
    __syncthreads();   // c=0: all waves done reading As/Bs (K-loop) before ep writes
    if (wm == (c >> 1)) {
      int mfb = (c & 1) * 2;
#pragma unroll
      for (int mi = 0; mi < 2; ++mi) {
        int mf = mfb + mi;
        int rr0 = mf * 16 + quad * 4 - (c & 1) * 32;
#pragma unroll
        for (int nf = 0; nf < 4; ++nf) {
          int col = wn * 64 + nf * 16 + q15;
#pragma unroll
          for (int r = 0; r < 4; ++r)
            ep[(rr0 + r) * 132 + col] = acc[mf][nf][r];
        }
      }
    }
    __syncthreads();
    if (sel < 2) {
      // 256 threads = 32 rows x 8 col-groups of the lower half; each thread
      // emits lower AND upper outputs from one sincos per j.
      int s = s0 + c * 32 + rr;
      float sf = (float)s;
      float4 a0 = *(const float4*)&ep[rr * 132 + ocg];
      float4 a1 = *(const float4*)&ep[rr * 132 + ocg + 4];
      float4 b0 = *(const float4*)&ep[rr * 132 + ocg + 64];
      float4 b1 = *(const float4*)&ep[rr * 132 + ocg + 68];
      float t1[8] = {a0.x, a0.y, a0.z, a0.w, a1.x, a1.y, a1.z, a1.w};
      float t2[8] = {b0.x, b0.y, b0.z, b0.w, b1.x, b1.y, b1.z, b1.w};
      float scl = (sel == 0) ? CS : 1.0f;
      unsigned short lo[8], up[8];
#pragma unroll
      for (int j = 0; j < 8; ++j) {
        float ang = sf * invf[j];
        float cc = __cosf(ang), ss = __sinf(ang);
        lo[j] = f2bf((t1[j] * cc - t2[j] * ss) * scl);
        up[j] = f2bf((t2[j] * cc + t1[j] * ss) * scl);
      }
      unsigned short* dst = (sel == 0 ? Qo : Ko) + ((size_t)bh * SEQ + s) * HD + ocg;
      *(uint4*)dst = *(uint4*)lo;
      *(uint4*)(dst + 64) = *(uint4*)up;
    } else {
#pragma unroll
      for (int oi = 0; oi < 2; ++oi) {
        int o = oi * 256 + tid;
        int hd = o & 127, so8 = (o >> 7) * 8;
        unsigned short u[8];
#pragma unroll
        for (int k = 0; k < 8; ++k)
          u[k] = f2bf(ep[(so8 + k) * 132 + hd]);
        *(uint4*)(Vto + ((size_t)bh * HD + hd) * SEQ + (s0 + c * 32 + so8)) = *(uint4*)u;
      }
    }
  }
}

// ---------------------------------------------------------------- O-projection GEMM, 256x256 deep-pipelined (R4 core, unchanged)
#define STAGE8(buf, op, half, kt)                                               \
  do {                                                                          \
    const unsigned short* Gp = (op) ? Bw : A;                                   \
    const int rb = ((op) ? n0 : m0) + (half) * 128;                             \
    unsigned short* hb = sm + ((((buf) << 1) | (op)) * 2 + (half)) * 8192;      \
    _Pragma("unroll")                                                           \
    for (int jj = 0; jj < 2; ++jj) {                                            \
      int l = jj * 512 + tid;                                                   \
      int rr = l >> 3, cc = l & 7;                                              \
      int cs = cc ^ (rr & 7);                                                   \
      async16(&hb[l * 8], Gp + (size_t)(rb + rr) * DIM + (kt) * 64 + cs * 8);   \
    }                                                                           \
  } while (0)

#define RDA8(dst, buf, mf, ks)                                                  \
  do {                                                                          \
    int R = (mf) * 16 + q15;                                                    \
    int cc = ((ks) * 4 + quad) ^ (R & 7);                                       \
    dst = *(const bf16x8*)&sm[((((buf) << 1) | 0) * 2 + wm) * 8192 + (R * 8 + cc) * 8]; \
  } while (0)

#define RDB8(dst, buf, nf, ks)                                                  \
  do {                                                                          \
    int R = (wn & 1) * 64 + (nf) * 16 + q15;                                    \
    int cc = ((ks) * 4 + quad) ^ (R & 7);                                       \
    dst = *(const bf16x8*)&sm[((((buf) << 1) | 1) * 2 + (wn >> 1)) * 8192 + (R * 8 + cc) * 8]; \
  } while (0)

#define MFMA_Q(mlo, nlo)                                                        \
  do {                                                                          \
    __builtin_amdgcn_s_barrier();                                               \
    asm volatile("s_waitcnt lgkmcnt(0)" ::: "memory");                          \
    __builtin_amdgcn_s_setprio(1);                                              \
    _Pragma("unroll")                                                           \
    for (int ks = 0; ks < 2; ++ks)                                              \
      _Pragma("unroll")                                                         \
      for (int mi = 0; mi < 4; ++mi)                                            \
        _Pragma("unroll")                                                       \
        for (int ni = 0; ni < 2; ++ni)                                          \
          acc[(mlo) + mi][(nlo) + ni] = __builtin_amdgcn_mfma_f32_16x16x32_bf16( \
              af[(mlo) + mi][ks], bfr[(nlo) + ni][ks], acc[(mlo) + mi][(nlo) + ni], 0, 0, 0); \
    __builtin_amdgcn_s_setprio(0);                                              \
    __builtin_amdgcn_s_barrier();                                               \
  } while (0)

__global__ __launch_bounds__(512, 2) void gemm_out(
    const unsigned short* __restrict__ A,
    const unsigned short* __restrict__ Bw,
    float* __restrict__ outf,
    const float* __restrict__ bias) {
  extern __shared__ unsigned short sm[];   // [buf][op][half][128*64] = 128 KiB
  const int tid = threadIdx.x;
  const int lane = tid & 63;
  const int wv = tid >> 6;
  const int q15 = lane & 15, quad = lane >> 4;
  const int wm = wv >> 2, wn = wv & 3;     // 2 x 4 wave grid; wave tile 128x64
  const int n0 = blockIdx.x * 256, m0 = blockIdx.y * 256;

  f32x4 acc[8][4] = {};
  bf16x8 af[8][2], bfr[4][2];

  STAGE8(0, 0, 0, 0); STAGE8(0, 0, 1, 0); STAGE8(0, 1, 0, 0); STAGE8(0, 1, 1, 0);
  STAGE8(1, 0, 0, 1); STAGE8(1, 0, 1, 1);
  asm volatile("s_waitcnt vmcnt(4)" ::: "memory");
  __builtin_amdgcn_s_barrier();

  for (int T = 0; T < 32; ++T) {
    const int buf = T & 1;
#pragma unroll
    for (int mf = 0; mf < 4; ++mf) { RDA8(af[mf][0], buf, mf, 0); RDA8(af[mf][1], buf, mf, 1); }
#pragma unroll
    for (int nf = 0; nf < 2; ++nf) { RDB8(bfr[nf][0], buf, nf, 0); RDB8(bfr[nf][1], buf, nf, 1); }
    if (T + 1 < 32) STAGE8(buf ^ 1, 1, 0, T + 1);
    MFMA_Q(0, 0);
#pragma unroll
    for (int mf = 4; mf < 8; ++mf) { RDA8(af[mf][0], buf, mf, 0); RDA8(af[mf][1], buf, mf, 1); }
#pragma unroll
    for (int nf = 2; nf < 4; ++nf) { RDB8(bfr[nf][0], buf, nf, 0); RDB8(bfr[nf][1], buf, nf, 1); }
    if (T + 1 < 32) STAGE8(buf ^ 1, 1, 1, T + 1);
    MFMA_Q(0, 2);
    if (T + 2 < 32) STAGE8(buf, 0, 0, T + 2);
    MFMA_Q(4, 2);
    if (T + 2 < 32) STAGE8(buf, 0, 1, T + 2);
    if (T < 30) { asm volatile("s_waitcnt vmcnt(4)" ::: "memory"); }
    else if (T == 30) { asm volatile("s_waitcnt vmcnt(0)" ::: "memory"); }
    MFMA_Q(4, 0);
  }

  float bv[4];
#pragma unroll
  for (int nf = 0; nf < 4; ++nf) bv[nf] = bias[n0 + wn * 64 + nf * 16 + q15];
#pragma unroll
  for (int mf = 0; mf < 8; ++mf)
#pragma unroll
    for (int nf = 0; nf < 4; ++nf) {
      int col = n0 + wn * 64 + nf * 16 + q15;
      int row = m0 + wm * 128 + mf * 16 + quad * 4;
#pragma unroll
      for (int r = 0; r < 4; ++r)
        outf[(size_t)(row + r) * DIM + col] = acc[mf][nf][r] + bv[nf];
    }
}

// ---------------------------------------------------------------- flash attention (R0 structure — known-good ~255us)
// R5/R6 lessons: dbuf-K lost a block/CU (-31us); 4-barrier single-buffer
// pipeline added 2 barriers/tile and lost ~24us. At 3 blocks/CU the TLP
// already hides most staging latency — do not edit this kernel's sync
// structure further.
__global__ __launch_bounds__(256) void attn_kernel(
    const unsigned short* __restrict__ Q,    // (B*H, S, HD) rope'd * CS
    const unsigned short* __restrict__ Kg,   // (B*H, S, HD) rope'd
    const unsigned short* __restrict__ Vt,   // (B*H, HD, S)
    unsigned short* __restrict__ O) {        // (B, S, H, HD) bf16
  __shared__ unsigned short Ks[64 * 128];
  __shared__ unsigned short Vs[128 * 64];
  __shared__ unsigned short Ps[4 * 32 * 72];
  const int tid = threadIdx.x;
  const int lane = tid & 63, wv = tid >> 6;
  const int q15 = lane & 15, quad = lane >> 4;
  const int bh = blockIdx.x & 63;
  const int t = blockIdx.x >> 6;             // 0..11
  const int nseg = (t < 8) ? 1 : 2;
  const int b = bh >> 4, h = bh & 15;
  unsigned short* Pw = Ps + wv * (32 * 72);

  for (int seg = 0; seg < nseg; ++seg) {
    const int qt = (t < 8) ? (15 - t) : (seg == 0 ? (15 - t) : (t - 8));
    const int q0w = qt * 128 + wv * 32;

    bf16x8 qf[2][4];
#pragma unroll
    for (int nq = 0; nq < 2; ++nq) {
      const unsigned short* qp = Q + ((size_t)bh * SEQ + q0w + nq * 16 + q15) * HD + quad * 8;
#pragma unroll
      for (int ks = 0; ks < 4; ++ks) qf[nq][ks] = *(const bf16x8*)(qp + ks * 32);
    }

    f32x4 oacc[2][8] = {};
    float rs[2] = {0.f, 0.f};
    const int jmax = 2 * qt + 2;
    const int jcap = 2 * qt + (wv >> 1);

    for (int j = 0; j < jmax; ++j) {
      const int kv0 = j * 64;
      __syncthreads();
#pragma unroll
      for (int i = 0; i < 4; ++i) {
        int l = i * 256 + tid;
        int r = l >> 4, c = (l & 15) ^ (r & 15);
        async16(&Ks[l * 8], Kg + ((size_t)bh * SEQ + kv0 + r) * HD + c * 8);
      }
#pragma unroll
      for (int i = 0; i < 4; ++i) {
        int l = i * 256 + tid;
        int r = l >> 3, c = (l & 7) ^ (r & 7);
        async16(&Vs[l * 8], Vt + ((size_t)bh * HD + r) * SEQ + kv0 + c * 8);
      }
      __syncthreads();

      if (j <= jcap) {
        const bool edge = (j == jcap);
#pragma unroll
        for (int mi = 0; mi < 4; ++mi) {
          f32x4 st[2] = {};
#pragma unroll
          for (int ks = 0; ks < 4; ++ks) {
            int r = mi * 16 + q15;
            int c = ks * 4 + quad;
            bf16x8 kf = *(const bf16x8*)&Ks[(r * 16 + (c ^ (r & 15))) * 8];
#pragma unroll
            for (int nq = 0; nq < 2; ++nq)
              st[nq] = __builtin_amdgcn_mfma_f32_16x16x32_bf16(kf, qf[nq][ks], st[nq], 0, 0, 0);
          }
#pragma unroll
          for (int nq = 0; nq < 2; ++nq) {
            unsigned int u[4];
#pragma unroll
            for (int r = 0; r < 4; ++r) {
              float p = exp2f(st[nq][r]);
              if (edge) {
                int kv = kv0 + mi * 16 + quad * 4 + r;
                int qq = q0w + nq * 16 + q15;
                p = (kv > qq) ? 0.f : p;
              }
              unsigned int uu = __builtin_bit_cast(unsigned int, p) & 0xffff0000u;
              rs[nq] += __builtin_bit_cast(float, uu);
              u[r] = uu;
            }
            uint2 pk;
            pk.x = (u[0] >> 16) | u[1];
            pk.y = (u[2] >> 16) | u[3];
            *(uint2*)&Pw[(nq * 16 + q15) * 72 + mi * 16 + quad * 4] = pk;
          }
        }
#pragma unroll
        for (int ks = 0; ks < 2; ++ks) {
          bf16x8 pf[2];
#pragma unroll
          for (int mq = 0; mq < 2; ++mq)
            pf[mq] = *(const bf16x8*)&Pw[(mq * 16 + q15) * 72 + ks * 32 + quad * 8];
#pragma unroll
          for (int nf = 0; nf < 8; ++nf) {
            int r = nf * 16 + q15;
            int c = ks * 4 + quad;
            bf16x8 vf = *(const bf16x8*)&Vs[(r * 8 + (c ^ (r & 7))) * 8];
#pragma unroll
            for (int mq = 0; mq < 2; ++mq)
              oacc[mq][nf] = __builtin_amdgcn_mfma_f32_16x16x32_bf16(pf[mq], vf, oacc[mq][nf], 0, 0, 0);
          }
        }
      }
    }

    // segment epilogue: reduce row sums across quads, write O
#pragma unroll
    for (int nq = 0; nq < 2; ++nq) {
      rs[nq] += __shfl_xor(rs[nq], 16);
      rs[nq] += __shfl_xor(rs[nq], 32);
    }
#pragma unroll
    for (int mq = 0; mq < 2; ++mq) {
#pragma unroll
      for (int r = 0; r < 4; ++r) {
        float l = __shfl(rs[mq], quad * 4 + r);
        float inv = 1.0f / l;
        int qq = q0w + mq * 16 + quad * 4 + r;
        size_t base = (((size_t)b * SEQ + qq) * NH + h) * HD;
#pragma unroll
        for (int nf = 0; nf < 8; ++nf)
          O[base + nf * 16 + q15] = f2bf(oacc[mq][nf][r] * inv);
      }
    }
  }
}

// ---------------------------------------------------------------- launch
extern "C" void kernel_launch(void* const* d_in, const int* in_sizes, int n_in,
                              void* d_out, int out_size, void* d_ws, size_t ws_size,
                              hipStream_t stream) {
  (void)in_sizes; (void)n_in; (void)out_size; (void)ws_size;
  const float* x  = (const float*)d_in[0];
  const float* Wq = (const float*)d_in[1];
  const float* Wk = (const float*)d_in[2];
  const float* Wv = (const float*)d_in[3];
  const float* Wo = (const float*)d_in[4];
  const float* bo = (const float*)d_in[5];
  float* out = (float*)d_out;

  const size_t XE = (size_t)BATCH * SEQ * DIM;   // 16.7M elems
  const size_t WE = (size_t)DIM * DIM;           // 4.2M elems

  char* p = (char*)d_ws;
  unsigned short* xb   = (unsigned short*)p; p += XE * 2;
  unsigned short* Wall = (unsigned short*)p; p += 4 * WE * 2;
  unsigned short* Qg   = (unsigned short*)p; p += XE * 2;
  unsigned short* Kb   = (unsigned short*)p; p += XE * 2;
  unsigned short* Vtb  = (unsigned short*)p; p += XE * 2;
  unsigned short* attn = (unsigned short*)p; p += XE * 2;

  static bool attr_set = false;
  if (!attr_set) {
    hipFuncSetAttribute((const void*)gemm_out,
                        hipFuncAttributeMaxDynamicSharedMemorySize, 131072);
    attr_set = true;
  }

  cast_all_kernel<<<(int)(2 * XE / 4 / 256), 256, 0, stream>>>(x, Wq, Wk, Wv, Wo, xb);

  gemm_qkv<<<dim3(48, 64), 256, 0, stream>>>(
      xb, Wall, Wall + WE, Wall + 2 * WE, Qg, Kb, Vtb);

  attn_kernel<<<dim3(768), 256, 0, stream>>>(Qg, Kb, Vtb, attn);

  gemm_out<<<dim3(DIM / 256, (BATCH * SEQ) / 256), 512, 131072, stream>>>(
      attn, Wall + 3 * WE, out, bo);
}

// Round 9
// 674.183 us; speedup vs baseline: 1.0634x; 1.0634x over previous
//
#include <hip/hip_runtime.h>

#define BATCH 4
#define SEQ   2048
#define DIM   2048
#define NH    16
#define HD    128

typedef __bf16 bf16x8 __attribute__((ext_vector_type(8)));
typedef float  f32x4  __attribute__((ext_vector_type(4)));

__device__ __forceinline__ unsigned short f2bf(float f) {
  unsigned int u = __builtin_bit_cast(unsigned int, f);
  u += 0x7fffu + ((u >> 16) & 1u);          // RNE
  return (unsigned short)(u >> 16);
}

// async global->LDS, 16B per lane; LDS dest must be wave-uniform-base + lane*16
__device__ __forceinline__ void async16(void* lds, const void* g) {
  __builtin_amdgcn_global_load_lds(
      (const __attribute__((address_space(1))) unsigned int*)g,
      (__attribute__((address_space(3))) unsigned int*)lds, 16, 0, 0);
}

// ---------------------------------------------------------------- one cast dispatch for x + all 4 weights
__global__ __launch_bounds__(256) void cast_all_kernel(
    const float* __restrict__ x,
    const float* __restrict__ w0, const float* __restrict__ w1,
    const float* __restrict__ w2, const float* __restrict__ w3,
    unsigned short* __restrict__ dst) {
  int i = blockIdx.x * 256 + threadIdx.x;
  const float* s;
  int loc;
  if (i < (1 << 22)) { s = x; loc = i; }
  else {
    int k = i - (1 << 22);
    int sel = k >> 20; loc = k & 0xfffff;
    s = sel == 0 ? w0 : sel == 1 ? w1 : sel == 2 ? w2 : w3;
  }
  float4 v = ((const float4*)s)[loc];
  ushort4 o;
  o.x = f2bf(v.x); o.y = f2bf(v.y); o.z = f2bf(v.z); o.w = f2bf(v.w);
  ((ushort4*)dst)[i] = o;
}

// ---------------------------------------------------------------- fused QKV GEMM + RoPE + V-transpose
// R9: reverted verbatim to the R4 version (measured best: 294.6us, VGPR 68).
// R7 lesson: LDS aliasing was occupancy-neutral (metric doesn't respond to
// static limits). R8 lesson: dual-half RoPE dedup inflated VGPR 68->92 ->
// waves/SIMD 7->5 -> -38us; epilogue register state taxes K-loop occupancy.
__global__ __launch_bounds__(256) void gemm_qkv(
    const unsigned short* __restrict__ A,    // xb (8192 x 2048) bf16
    const unsigned short* __restrict__ Wq,
    const unsigned short* __restrict__ Wk,
    const unsigned short* __restrict__ Wv,
    unsigned short* __restrict__ Qo,
    unsigned short* __restrict__ Ko,
    unsigned short* __restrict__ Vto) {
  __shared__ unsigned short As[128 * 32];
  __shared__ unsigned short Bs[128 * 32];
  __shared__ float ep[32 * 132];
  const int tid = threadIdx.x;
  const int lane = tid & 63, wv = tid >> 6;
  const int q15 = lane & 15, quad = lane >> 4;
  const int wm = wv >> 1, wn = wv & 1;
  const int gx = blockIdx.x;
  const int sel = gx >> 4, h = gx & 15;
  const int m0 = blockIdx.y * 128;
  const unsigned short* Bw =
      (sel == 0 ? Wq : (sel == 1 ? Wk : Wv)) + (size_t)h * 128 * DIM;

  f32x4 acc[4][4] = {};

  for (int kt = 0; kt < DIM; kt += 32) {
    __syncthreads();
#pragma unroll
    for (int i = 0; i < 2; ++i) {
      int l = i * 256 + tid;
      int r = l >> 2, s = l & 3;
      int c = (s - (r >> 1)) & 3;
      async16(&As[l * 8], A + (size_t)(m0 + r) * DIM + kt + c * 8);
    }
#pragma unroll
    for (int i = 0; i < 2; ++i) {
      int l = i * 256 + tid;
      int r = l >> 2, s = l & 3;
      int c = (s - (r >> 1)) & 3;
      async16(&Bs[l * 8], Bw + (size_t)r * DIM + kt + c * 8);
    }
    __syncthreads();

    bf16x8 af[4], bf[4];
#pragma unroll
    for (int mf = 0; mf < 4; ++mf) {
      int r = wm * 64 + mf * 16 + q15;
      int sl = r * 4 + ((quad + (r >> 1)) & 3);
      af[mf] = *(const bf16x8*)&As[sl * 8];
    }
#pragma unroll
    for (int nf = 0; nf < 4; ++nf) {
      int r = wn * 64 + nf * 16 + q15;
      int sl = r * 4 + ((quad + (r >> 1)) & 3);
      bf[nf] = *(const bf16x8*)&Bs[sl * 8];
    }
#pragma unroll
    for (int mf = 0; mf < 4; ++mf)
#pragma unroll
      for (int nf = 0; nf < 4; ++nf)
        acc[mf][nf] = __builtin_amdgcn_mfma_f32_16x16x32_bf16(af[mf], bf[nf], acc[mf][nf], 0, 0, 0);
  }

  const int b = m0 >> 11;
  const int s0 = m0 & (SEQ - 1);
  const int bh = b * NH + h;
  const float CS = 0.12751744f;

  float invf[2][8];
  if (sel < 2) {
#pragma unroll
    for (int oi = 0; oi < 2; ++oi) {
      int oc = ((oi * 256 + tid) & 15) * 8;
#pragma unroll
      for (int j = 0; j < 8; ++j)
        invf[oi][j] = exp2f(-(float)((oc & 63) + j) * 0.20762050593046932f);
    }
  }

  for (int c = 0; c < 4; ++c) {
    __syncthreads();
    if (wm == (c >> 1)) {
      int mfb = (c & 1) * 2;
#pragma unroll
      for (int mi = 0; mi < 2; ++mi) {
        int mf = mfb + mi;
        int rr0 = mf * 16 + quad * 4 - (c & 1) * 32;
#pragma unroll
        for (int nf = 0; nf < 4; ++nf) {
          int col = wn * 64 + nf * 16 + q15;
#pragma unroll
          for (int r = 0; r < 4; ++r)
            ep[(rr0 + r) * 132 + col] = acc[mf][nf][r];
        }
      }
    }
    __syncthreads();
#pragma unroll
    for (int oi = 0; oi < 2; ++oi) {
      int o = oi * 256 + tid;
      if (sel < 2) {
        int rr = o >> 4, oc = (o & 15) * 8;
        int s = s0 + c * 32 + rr;
        float sf = (float)s;
        float4 a0 = *(const float4*)&ep[rr * 132 + oc];
        float4 a1 = *(const float4*)&ep[rr * 132 + oc + 4];
        float4 b0 = *(const float4*)&ep[rr * 132 + (oc ^ 64)];
        float4 b1 = *(const float4*)&ep[rr * 132 + (oc ^ 64) + 4];
        float av[8] = {a0.x, a0.y, a0.z, a0.w, a1.x, a1.y, a1.z, a1.w};
        float bv[8] = {b0.x, b0.y, b0.z, b0.w, b1.x, b1.y, b1.z, b1.w};
        float sgn = (oc & 64) ? 1.f : -1.f;
        float scl = (sel == 0) ? CS : 1.0f;
        unsigned short u[8];
#pragma unroll
        for (int j = 0; j < 8; ++j) {
          float ang = sf * invf[oi][j];
          float cc = __cosf(ang), ss = __sinf(ang);
          u[j] = f2bf((av[j] * cc + sgn * bv[j] * ss) * scl);
        }
        unsigned short* dst = (sel == 0 ? Qo : Ko) + ((size_t)bh * SEQ + s) * HD + oc;
        *(uint4*)dst = *(uint4*)u;
      } else {
        int hd = o & 127, so8 = (o >> 7) * 8;
        unsigned short u[8];
#pragma unroll
        for (int k = 0; k < 8; ++k)
          u[k] = f2bf(ep[(so8 + k) * 132 + hd]);
        *(uint4*)(Vto + ((size_t)bh * HD + hd) * SEQ + (s0 + c * 32 + so8)) = *(uint4*)u;
      }
    }
  }
}

// ---------------------------------------------------------------- O-projection GEMM, 256x256 deep-pipelined (R4 core)
#define STAGE8(buf, op, half, kt)                                               \
  do {                                                                          \
    const unsigned short* Gp = (op) ? Bw : A;                                   \
    const int rb = ((op) ? n0 : m0) + (half) * 128;                             \
    unsigned short* hb = sm + ((((buf) << 1) | (op)) * 2 + (half)) * 8192;      \
    _Pragma("unroll")                                                           \
    for (int jj = 0; jj < 2; ++jj) {                                            \
      int l = jj * 512 + tid;                                                   \
      int rr = l >> 3, cc = l & 7;                                              \
      int cs = cc ^ (rr & 7);                                                   \
      async16(&hb[l * 8], Gp + (size_t)(rb + rr) * DIM + (kt) * 64 + cs * 8);   \
    }                                                                           \
  } while (0)

#define RDA8(dst, buf, mf, ks)                                                  \
  do {                                                                          \
    int R = (mf) * 16 + q15;                                                    \
    int cc = ((ks) * 4 + quad) ^ (R & 7);                                       \
    dst = *(const bf16x8*)&sm[((((buf) << 1) | 0) * 2 + wm) * 8192 + (R * 8 + cc) * 8]; \
  } while (0)

#define RDB8(dst, buf, nf, ks)                                                  \
  do {                                                                          \
    int R = (wn & 1) * 64 + (nf) * 16 + q15;                                    \
    int cc = ((ks) * 4 + quad) ^ (R & 7);                                       \
    dst = *(const bf16x8*)&sm[((((buf) << 1) | 1) * 2 + (wn >> 1)) * 8192 + (R * 8 + cc) * 8]; \
  } while (0)

#define MFMA_Q(mlo, nlo)                                                        \
  do {                                                                          \
    __builtin_amdgcn_s_barrier();                                               \
    asm volatile("s_waitcnt lgkmcnt(0)" ::: "memory");                          \
    __builtin_amdgcn_s_setprio(1);                                              \
    _Pragma("unroll")                                                           \
    for (int ks = 0; ks < 2; ++ks)                                              \
      _Pragma("unroll")                                                         \
      for (int mi = 0; mi < 4; ++mi)                                            \
        _Pragma("unroll")                                                       \
        for (int ni = 0; ni < 2; ++ni)                                          \
          acc[(mlo) + mi][(nlo) + ni] = __builtin_amdgcn_mfma_f32_16x16x32_bf16( \
              af[(mlo) + mi][ks], bfr[(nlo) + ni][ks], acc[(mlo) + mi][(nlo) + ni], 0, 0, 0); \
    __builtin_amdgcn_s_setprio(0);                                              \
    __builtin_amdgcn_s_barrier();                                               \
  } while (0)

__global__ __launch_bounds__(512, 2) void gemm_out(
    const unsigned short* __restrict__ A,
    const unsigned short* __restrict__ Bw,
    float* __restrict__ outf,
    const float* __restrict__ bias) {
  extern __shared__ unsigned short sm[];   // [buf][op][half][128*64] = 128 KiB
  const int tid = threadIdx.x;
  const int lane = tid & 63;
  const int wv = tid >> 6;
  const int q15 = lane & 15, quad = lane >> 4;
  const int wm = wv >> 2, wn = wv & 3;     // 2 x 4 wave grid; wave tile 128x64
  const int n0 = blockIdx.x * 256, m0 = blockIdx.y * 256;

  f32x4 acc[8][4] = {};
  bf16x8 af[8][2], bfr[4][2];

  STAGE8(0, 0, 0, 0); STAGE8(0, 0, 1, 0); STAGE8(0, 1, 0, 0); STAGE8(0, 1, 1, 0);
  STAGE8(1, 0, 0, 1); STAGE8(1, 0, 1, 1);
  asm volatile("s_waitcnt vmcnt(4)" ::: "memory");
  __builtin_amdgcn_s_barrier();

  for (int T = 0; T < 32; ++T) {
    const int buf = T & 1;
#pragma unroll
    for (int mf = 0; mf < 4; ++mf) { RDA8(af[mf][0], buf, mf, 0); RDA8(af[mf][1], buf, mf, 1); }
#pragma unroll
    for (int nf = 0; nf < 2; ++nf) { RDB8(bfr[nf][0], buf, nf, 0); RDB8(bfr[nf][1], buf, nf, 1); }
    if (T + 1 < 32) STAGE8(buf ^ 1, 1, 0, T + 1);
    MFMA_Q(0, 0);
#pragma unroll
    for (int mf = 4; mf < 8; ++mf) { RDA8(af[mf][0], buf, mf, 0); RDA8(af[mf][1], buf, mf, 1); }
#pragma unroll
    for (int nf = 2; nf < 4; ++nf) { RDB8(bfr[nf][0], buf, nf, 0); RDB8(bfr[nf][1], buf, nf, 1); }
    if (T + 1 < 32) STAGE8(buf ^ 1, 1, 1, T + 1);
    MFMA_Q(0, 2);
    if (T + 2 < 32) STAGE8(buf, 0, 0, T + 2);
    MFMA_Q(4, 2);
    if (T + 2 < 32) STAGE8(buf, 0, 1, T + 2);
    if (T < 30) { asm volatile("s_waitcnt vmcnt(4)" ::: "memory"); }
    else if (T == 30) { asm volatile("s_waitcnt vmcnt(0)" ::: "memory"); }
    MFMA_Q(4, 0);
  }

  float bv[4];
#pragma unroll
  for (int nf = 0; nf < 4; ++nf) bv[nf] = bias[n0 + wn * 64 + nf * 16 + q15];
#pragma unroll
  for (int mf = 0; mf < 8; ++mf)
#pragma unroll
    for (int nf = 0; nf < 4; ++nf) {
      int col = n0 + wn * 64 + nf * 16 + q15;
      int row = m0 + wm * 128 + mf * 16 + quad * 4;
#pragma unroll
      for (int r = 0; r < 4; ++r)
        outf[(size_t)(row + r) * DIM + col] = acc[mf][nf][r] + bv[nf];
    }
}

// ---------------------------------------------------------------- flash attention (R0 structure — known-good ~255us)
// R5/R6 lessons: dbuf-K lost a block/CU (-31us); 4-barrier single-buffer
// pipeline added 2 barriers/tile (-24us). At 3 blocks/CU the TLP already
// hides staging latency — sync-structure edits on this kernel only subtract.
__global__ __launch_bounds__(256) void attn_kernel(
    const unsigned short* __restrict__ Q,    // (B*H, S, HD) rope'd * CS
    const unsigned short* __restrict__ Kg,   // (B*H, S, HD) rope'd
    const unsigned short* __restrict__ Vt,   // (B*H, HD, S)
    unsigned short* __restrict__ O) {        // (B, S, H, HD) bf16
  __shared__ unsigned short Ks[64 * 128];
  __shared__ unsigned short Vs[128 * 64];
  __shared__ unsigned short Ps[4 * 32 * 72];
  const int tid = threadIdx.x;
  const int lane = tid & 63, wv = tid >> 6;
  const int q15 = lane & 15, quad = lane >> 4;
  const int bh = blockIdx.x & 63;
  const int t = blockIdx.x >> 6;             // 0..11
  const int nseg = (t < 8) ? 1 : 2;
  const int b = bh >> 4, h = bh & 15;
  unsigned short* Pw = Ps + wv * (32 * 72);

  for (int seg = 0; seg < nseg; ++seg) {
    const int qt = (t < 8) ? (15 - t) : (seg == 0 ? (15 - t) : (t - 8));
    const int q0w = qt * 128 + wv * 32;

    bf16x8 qf[2][4];
#pragma unroll
    for (int nq = 0; nq < 2; ++nq) {
      const unsigned short* qp = Q + ((size_t)bh * SEQ + q0w + nq * 16 + q15) * HD + quad * 8;
#pragma unroll
      for (int ks = 0; ks < 4; ++ks) qf[nq][ks] = *(const bf16x8*)(qp + ks * 32);
    }

    f32x4 oacc[2][8] = {};
    float rs[2] = {0.f, 0.f};
    const int jmax = 2 * qt + 2;
    const int jcap = 2 * qt + (wv >> 1);

    for (int j = 0; j < jmax; ++j) {
      const int kv0 = j * 64;
      __syncthreads();
#pragma unroll
      for (int i = 0; i < 4; ++i) {
        int l = i * 256 + tid;
        int r = l >> 4, c = (l & 15) ^ (r & 15);
        async16(&Ks[l * 8], Kg + ((size_t)bh * SEQ + kv0 + r) * HD + c * 8);
      }
#pragma unroll
      for (int i = 0; i < 4; ++i) {
        int l = i * 256 + tid;
        int r = l >> 3, c = (l & 7) ^ (r & 7);
        async16(&Vs[l * 8], Vt + ((size_t)bh * HD + r) * SEQ + kv0 + c * 8);
      }
      __syncthreads();

      if (j <= jcap) {
        const bool edge = (j == jcap);
#pragma unroll
        for (int mi = 0; mi < 4; ++mi) {
          f32x4 st[2] = {};
#pragma unroll
          for (int ks = 0; ks < 4; ++ks) {
            int r = mi * 16 + q15;
            int c = ks * 4 + quad;
            bf16x8 kf = *(const bf16x8*)&Ks[(r * 16 + (c ^ (r & 15))) * 8];
#pragma unroll
            for (int nq = 0; nq < 2; ++nq)
              st[nq] = __builtin_amdgcn_mfma_f32_16x16x32_bf16(kf, qf[nq][ks], st[nq], 0, 0, 0);
          }
#pragma unroll
          for (int nq = 0; nq < 2; ++nq) {
            unsigned int u[4];
#pragma unroll
            for (int r = 0; r < 4; ++r) {
              float p = exp2f(st[nq][r]);
              if (edge) {
                int kv = kv0 + mi * 16 + quad * 4 + r;
                int qq = q0w + nq * 16 + q15;
                p = (kv > qq) ? 0.f : p;
              }
              unsigned int uu = __builtin_bit_cast(unsigned int, p) & 0xffff0000u;
              rs[nq] += __builtin_bit_cast(float, uu);
              u[r] = uu;
            }
            uint2 pk;
            pk.x = (u[0] >> 16) | u[1];
            pk.y = (u[2] >> 16) | u[3];
            *(uint2*)&Pw[(nq * 16 + q15) * 72 + mi * 16 + quad * 4] = pk;
          }
        }
#pragma unroll
        for (int ks = 0; ks < 2; ++ks) {
          bf16x8 pf[2];
#pragma unroll
          for (int mq = 0; mq < 2; ++mq)
            pf[mq] = *(const bf16x8*)&Pw[(mq * 16 + q15) * 72 + ks * 32 + quad * 8];
#pragma unroll
          for (int nf = 0; nf < 8; ++nf) {
            int r = nf * 16 + q15;
            int c = ks * 4 + quad;
            bf16x8 vf = *(const bf16x8*)&Vs[(r * 8 + (c ^ (r & 7))) * 8];
#pragma unroll
            for (int mq = 0; mq < 2; ++mq)
              oacc[mq][nf] = __builtin_amdgcn_mfma_f32_16x16x32_bf16(pf[mq], vf, oacc[mq][nf], 0, 0, 0);
          }
        }
      }
    }

    // segment epilogue: reduce row sums across quads, write O
#pragma unroll
    for (int nq = 0; nq < 2; ++nq) {
      rs[nq] += __shfl_xor(rs[nq], 16);
      rs[nq] += __shfl_xor(rs[nq], 32);
    }
#pragma unroll
    for (int mq = 0; mq < 2; ++mq) {
#pragma unroll
      for (int r = 0; r < 4; ++r) {
        float l = __shfl(rs[mq], quad * 4 + r);
        float inv = 1.0f / l;
        int qq = q0w + mq * 16 + quad * 4 + r;
        size_t base = (((size_t)b * SEQ + qq) * NH + h) * HD;
#pragma unroll
        for (int nf = 0; nf < 8; ++nf)
          O[base + nf * 16 + q15] = f2bf(oacc[mq][nf][r] * inv);
      }
    }
  }
}

// ---------------------------------------------------------------- launch
extern "C" void kernel_launch(void* const* d_in, const int* in_sizes, int n_in,
                              void* d_out, int out_size, void* d_ws, size_t ws_size,
                              hipStream_t stream) {
  (void)in_sizes; (void)n_in; (void)out_size; (void)ws_size;
  const float* x  = (const float*)d_in[0];
  const float* Wq = (const float*)d_in[1];
  const float* Wk = (const float*)d_in[2];
  const float* Wv = (const float*)d_in[3];
  const float* Wo = (const float*)d_in[4];
  const float* bo = (const float*)d_in[5];
  float* out = (float*)d_out;

  const size_t XE = (size_t)BATCH * SEQ * DIM;   // 16.7M elems
  const size_t WE = (size_t)DIM * DIM;           // 4.2M elems

  char* p = (char*)d_ws;
  unsigned short* xb   = (unsigned short*)p; p += XE * 2;
  unsigned short* Wall = (unsigned short*)p; p += 4 * WE * 2;
  unsigned short* Qg   = (unsigned short*)p; p += XE * 2;
  unsigned short* Kb   = (unsigned short*)p; p += XE * 2;
  unsigned short* Vtb  = (unsigned short*)p; p += XE * 2;
  unsigned short* attn = (unsigned short*)p; p += XE * 2;

  static bool attr_set = false;
  if (!attr_set) {
    hipFuncSetAttribute((const void*)gemm_out,
                        hipFuncAttributeMaxDynamicSharedMemorySize, 131072);
    attr_set = true;
  }

  cast_all_kernel<<<(int)(2 * XE / 4 / 256), 256, 0, stream>>>(x, Wq, Wk, Wv, Wo, xb);

  gemm_qkv<<<dim3(48, 64), 256, 0, stream>>>(
      xb, Wall, Wall + WE, Wall + 2 * WE, Qg, Kb, Vtb);

  attn_kernel<<<dim3(768), 256, 0, stream>>>(Qg, Kb, Vtb, attn);

  gemm_out<<<dim3(DIM / 256, (BATCH * SEQ) / 256), 512, 131072, stream>>>(
      attn, Wall + 3 * WE, out, bo);
}

// Round 10
// 610.720 us; speedup vs baseline: 1.1739x; 1.1039x over previous
//
#include <hip/hip_runtime.h>

#define BATCH 4
#define SEQ   2048
#define DIM   2048
#define NH    16
#define HD    128

typedef __bf16 bf16x8 __attribute__((ext_vector_type(8)));
typedef float  f32x4  __attribute__((ext_vector_type(4)));

__device__ __forceinline__ unsigned short f2bf(float f) {
  unsigned int u = __builtin_bit_cast(unsigned int, f);
  u += 0x7fffu + ((u >> 16) & 1u);          // RNE
  return (unsigned short)(u >> 16);
}

// async global->LDS, 16B per lane; LDS dest must be wave-uniform-base + lane*16
__device__ __forceinline__ void async16(void* lds, const void* g) {
  __builtin_amdgcn_global_load_lds(
      (const __attribute__((address_space(1))) unsigned int*)g,
      (__attribute__((address_space(3))) unsigned int*)lds, 16, 0, 0);
}

// ---------------------------------------------------------------- one cast dispatch for x + all 4 weights
__global__ __launch_bounds__(256) void cast_all_kernel(
    const float* __restrict__ x,
    const float* __restrict__ w0, const float* __restrict__ w1,
    const float* __restrict__ w2, const float* __restrict__ w3,
    unsigned short* __restrict__ dst) {
  int i = blockIdx.x * 256 + threadIdx.x;
  const float* s;
  int loc;
  if (i < (1 << 22)) { s = x; loc = i; }
  else {
    int k = i - (1 << 22);
    int sel = k >> 20; loc = k & 0xfffff;
    s = sel == 0 ? w0 : sel == 1 ? w1 : sel == 2 ? w2 : w3;
  }
  float4 v = ((const float4*)s)[loc];
  ushort4 o;
  o.x = f2bf(v.x); o.y = f2bf(v.y); o.z = f2bf(v.z); o.w = f2bf(v.w);
  ((ushort4*)dst)[i] = o;
}

// ---------------------------------------------------------------- fused QKV GEMM + RoPE + V-transpose (R4 version, unchanged)
// R8 lesson: dual-half RoPE dedup inflated VGPR 68->92 -> waves 7->5 -> -38us.
// R7 lesson: not LDS-occupancy-limited. Leave this kernel alone.
__global__ __launch_bounds__(256) void gemm_qkv(
    const unsigned short* __restrict__ A,    // xb (8192 x 2048) bf16
    const unsigned short* __restrict__ Wq,
    const unsigned short* __restrict__ Wk,
    const unsigned short* __restrict__ Wv,
    unsigned short* __restrict__ Qo,
    unsigned short* __restrict__ Ko,
    unsigned short* __restrict__ Vto) {
  __shared__ unsigned short As[128 * 32];
  __shared__ unsigned short Bs[128 * 32];
  __shared__ float ep[32 * 132];
  const int tid = threadIdx.x;
  const int lane = tid & 63, wv = tid >> 6;
  const int q15 = lane & 15, quad = lane >> 4;
  const int wm = wv >> 1, wn = wv & 1;
  const int gx = blockIdx.x;
  const int sel = gx >> 4, h = gx & 15;
  const int m0 = blockIdx.y * 128;
  const unsigned short* Bw =
      (sel == 0 ? Wq : (sel == 1 ? Wk : Wv)) + (size_t)h * 128 * DIM;

  f32x4 acc[4][4] = {};

  for (int kt = 0; kt < DIM; kt += 32) {
    __syncthreads();
#pragma unroll
    for (int i = 0; i < 2; ++i) {
      int l = i * 256 + tid;
      int r = l >> 2, s = l & 3;
      int c = (s - (r >> 1)) & 3;
      async16(&As[l * 8], A + (size_t)(m0 + r) * DIM + kt + c * 8);
    }
#pragma unroll
    for (int i = 0; i < 2; ++i) {
      int l = i * 256 + tid;
      int r = l >> 2, s = l & 3;
      int c = (s - (r >> 1)) & 3;
      async16(&Bs[l * 8], Bw + (size_t)r * DIM + kt + c * 8);
    }
    __syncthreads();

    bf16x8 af[4], bf[4];
#pragma unroll
    for (int mf = 0; mf < 4; ++mf) {
      int r = wm * 64 + mf * 16 + q15;
      int sl = r * 4 + ((quad + (r >> 1)) & 3);
      af[mf] = *(const bf16x8*)&As[sl * 8];
    }
#pragma unroll
    for (int nf = 0; nf < 4; ++nf) {
      int r = wn * 64 + nf * 16 + q15;
      int sl = r * 4 + ((quad + (r >> 1)) & 3);
      bf[nf] = *(const bf16x8*)&Bs[sl * 8];
    }
#pragma unroll
    for (int mf = 0; mf < 4; ++mf)
#pragma unroll
      for (int nf = 0; nf < 4; ++nf)
        acc[mf][nf] = __builtin_amdgcn_mfma_f32_16x16x32_bf16(af[mf], bf[nf], acc[mf][nf], 0, 0, 0);
  }

  const int b = m0 >> 11;
  const int s0 = m0 & (SEQ - 1);
  const int bh = b * NH + h;
  const float CS = 0.12751744f;

  float invf[2][8];
  if (sel < 2) {
#pragma unroll
    for (int oi = 0; oi < 2; ++oi) {
      int oc = ((oi * 256 + tid) & 15) * 8;
#pragma unroll
      for (int j = 0; j < 8; ++j)
        invf[oi][j] = exp2f(-(float)((oc & 63) + j) * 0.20762050593046932f);
    }
  }

  for (int c = 0; c < 4; ++c) {
    __syncthreads();
    if (wm == (c >> 1)) {
      int mfb = (c & 1) * 2;
#pragma unroll
      for (int mi = 0; mi < 2; ++mi) {
        int mf = mfb + mi;
        int rr0 = mf * 16 + quad * 4 - (c & 1) * 32;
#pragma unroll
        for (int nf = 0; nf < 4; ++nf) {
          int col = wn * 64 + nf * 16 + q15;
#pragma unroll
          for (int r = 0; r < 4; ++r)
            ep[(rr0 + r) * 132 + col] = acc[mf][nf][r];
        }
      }
    }
    __syncthreads();
#pragma unroll
    for (int oi = 0; oi < 2; ++oi) {
      int o = oi * 256 + tid;
      if (sel < 2) {
        int rr = o >> 4, oc = (o & 15) * 8;
        int s = s0 + c * 32 + rr;
        float sf = (float)s;
        float4 a0 = *(const float4*)&ep[rr * 132 + oc];
        float4 a1 = *(const float4*)&ep[rr * 132 + oc + 4];
        float4 b0 = *(const float4*)&ep[rr * 132 + (oc ^ 64)];
        float4 b1 = *(const float4*)&ep[rr * 132 + (oc ^ 64) + 4];
        float av[8] = {a0.x, a0.y, a0.z, a0.w, a1.x, a1.y, a1.z, a1.w};
        float bv[8] = {b0.x, b0.y, b0.z, b0.w, b1.x, b1.y, b1.z, b1.w};
        float sgn = (oc & 64) ? 1.f : -1.f;
        float scl = (sel == 0) ? CS : 1.0f;
        unsigned short u[8];
#pragma unroll
        for (int j = 0; j < 8; ++j) {
          float ang = sf * invf[oi][j];
          float cc = __cosf(ang), ss = __sinf(ang);
          u[j] = f2bf((av[j] * cc + sgn * bv[j] * ss) * scl);
        }
        unsigned short* dst = (sel == 0 ? Qo : Ko) + ((size_t)bh * SEQ + s) * HD + oc;
        *(uint4*)dst = *(uint4*)u;
      } else {
        int hd = o & 127, so8 = (o >> 7) * 8;
        unsigned short u[8];
#pragma unroll
        for (int k = 0; k < 8; ++k)
          u[k] = f2bf(ep[(so8 + k) * 132 + hd]);
        *(uint4*)(Vto + ((size_t)bh * HD + hd) * SEQ + (s0 + c * 32 + so8)) = *(uint4*)u;
      }
    }
  }
}

// ---------------------------------------------------------------- O-projection GEMM, 256x256 deep-pipelined
// R10: per-phase operand reads — af[4][2] reused (mf0-3 in P0, mf4-7 in P2;
// register WAR is wave-local), bA/bB pairs in P0/P1. Both A-half stages
// consolidated in P3 (A reads of tile T are complete at P2's end barrier, so
// the A-region overwrite stays issue-after-barrier, same invariant as R4).
// vmcnt ledger unchanged: at P3's vmcnt(4): A(T+1)+B(T+1)+A(T+2)=12 loads ->
// retires A(T+1),B(T+1), keeps A(T+2) in flight. Fragment VGPRs 96 -> 64
// (suspected spill edge: ~700 TF vs m201's 1563 at identical schedule shape).
#define STAGE8(buf, op, half, kt)                                               \
  do {                                                                          \
    const unsigned short* Gp = (op) ? Bw : A;                                   \
    const int rb = ((op) ? n0 : m0) + (half) * 128;                             \
    unsigned short* hb = sm + ((((buf) << 1) | (op)) * 2 + (half)) * 8192;      \
    _Pragma("unroll")                                                           \
    for (int jj = 0; jj < 2; ++jj) {                                            \
      int l = jj * 512 + tid;                                                   \
      int rr = l >> 3, cc = l & 7;                                              \
      int cs = cc ^ (rr & 7);                                                   \
      async16(&hb[l * 8], Gp + (size_t)(rb + rr) * DIM + (kt) * 64 + cs * 8);   \
    }                                                                           \
  } while (0)

#define RDA8(dst, buf, mf, ks)                                                  \
  do {                                                                          \
    int R = (mf) * 16 + q15;                                                    \
    int cc = ((ks) * 4 + quad) ^ (R & 7);                                       \
    dst = *(const bf16x8*)&sm[((((buf) << 1) | 0) * 2 + wm) * 8192 + (R * 8 + cc) * 8]; \
  } while (0)

#define RDB8(dst, buf, nf, ks)                                                  \
  do {                                                                          \
    int R = (wn & 1) * 64 + (nf) * 16 + q15;                                    \
    int cc = ((ks) * 4 + quad) ^ (R & 7);                                       \
    dst = *(const bf16x8*)&sm[((((buf) << 1) | 1) * 2 + (wn >> 1)) * 8192 + (R * 8 + cc) * 8]; \
  } while (0)

#define MFMA_Q2(mlo, nlo, BF)                                                   \
  do {                                                                          \
    __builtin_amdgcn_s_barrier();                                               \
    asm volatile("s_waitcnt lgkmcnt(0)" ::: "memory");                          \
    __builtin_amdgcn_s_setprio(1);                                              \
    _Pragma("unroll")                                                           \
    for (int ks = 0; ks < 2; ++ks)                                              \
      _Pragma("unroll")                                                         \
      for (int mi = 0; mi < 4; ++mi)                                            \
        _Pragma("unroll")                                                       \
        for (int ni = 0; ni < 2; ++ni)                                          \
          acc[(mlo) + mi][(nlo) + ni] = __builtin_amdgcn_mfma_f32_16x16x32_bf16( \
              af[mi][ks], BF[ni][ks], acc[(mlo) + mi][(nlo) + ni], 0, 0, 0);    \
    __builtin_amdgcn_s_setprio(0);                                              \
    __builtin_amdgcn_s_barrier();                                               \
  } while (0)

__global__ __launch_bounds__(512, 2) void gemm_out(
    const unsigned short* __restrict__ A,
    const unsigned short* __restrict__ Bw,
    float* __restrict__ outf,
    const float* __restrict__ bias) {
  extern __shared__ unsigned short sm[];   // [buf][op][half][128*64] = 128 KiB
  const int tid = threadIdx.x;
  const int lane = tid & 63;
  const int wv = tid >> 6;
  const int q15 = lane & 15, quad = lane >> 4;
  const int wm = wv >> 2, wn = wv & 3;     // 2 x 4 wave grid; wave tile 128x64
  const int n0 = blockIdx.x * 256, m0 = blockIdx.y * 256;

  f32x4 acc[8][4] = {};
  bf16x8 af[4][2], bA[2][2], bB[2][2];

  // prologue: tile0 (A h0,h1, B h0,h1) -> buf0; tile1 A halves -> buf1
  STAGE8(0, 0, 0, 0); STAGE8(0, 0, 1, 0); STAGE8(0, 1, 0, 0); STAGE8(0, 1, 1, 0);
  STAGE8(1, 0, 0, 1); STAGE8(1, 0, 1, 1);
  asm volatile("s_waitcnt vmcnt(4)" ::: "memory");   // tile0 resident; tile1 A in flight
  __builtin_amdgcn_s_barrier();

  for (int T = 0; T < 32; ++T) {
    const int buf = T & 1;
    // P0: read af(mf0-3) + bA(nf0-1); stage (T+1) B h0 -> buf^1; Q(0, bA)
#pragma unroll
    for (int mi = 0; mi < 4; ++mi) { RDA8(af[mi][0], buf, mi, 0); RDA8(af[mi][1], buf, mi, 1); }
#pragma unroll
    for (int ni = 0; ni < 2; ++ni) { RDB8(bA[ni][0], buf, ni, 0); RDB8(bA[ni][1], buf, ni, 1); }
    if (T + 1 < 32) STAGE8(buf ^ 1, 1, 0, T + 1);
    MFMA_Q2(0, 0, bA);
    // P1: read bB(nf2-3); stage (T+1) B h1 -> buf^1; Q(0, bB)
#pragma unroll
    for (int ni = 0; ni < 2; ++ni) { RDB8(bB[ni][0], buf, 2 + ni, 0); RDB8(bB[ni][1], buf, 2 + ni, 1); }
    if (T + 1 < 32) STAGE8(buf ^ 1, 1, 1, T + 1);
    MFMA_Q2(0, 2, bB);
    // P2: read af(mf4-7) overwriting af (wave-local WAR); no stage; Q(4, bB)
#pragma unroll
    for (int mi = 0; mi < 4; ++mi) { RDA8(af[mi][0], buf, 4 + mi, 0); RDA8(af[mi][1], buf, 4 + mi, 1); }
    MFMA_Q2(4, 2, bB);
    // P3: stage (T+2) A h0+h1 -> buf (A reads done at P2 end-barrier); counted vmcnt; Q(4, bA)
    if (T + 2 < 32) { STAGE8(buf, 0, 0, T + 2); STAGE8(buf, 0, 1, T + 2); }
    if (T < 30) { asm volatile("s_waitcnt vmcnt(4)" ::: "memory"); }
    else if (T == 30) { asm volatile("s_waitcnt vmcnt(0)" ::: "memory"); }
    MFMA_Q2(4, 0, bA);
  }

  float bv[4];
#pragma unroll
  for (int nf = 0; nf < 4; ++nf) bv[nf] = bias[n0 + wn * 64 + nf * 16 + q15];
#pragma unroll
  for (int mf = 0; mf < 8; ++mf)
#pragma unroll
    for (int nf = 0; nf < 4; ++nf) {
      int col = n0 + wn * 64 + nf * 16 + q15;
      int row = m0 + wm * 128 + mf * 16 + quad * 4;
#pragma unroll
      for (int r = 0; r < 4; ++r)
        outf[(size_t)(row + r) * DIM + col] = acc[mf][nf][r] + bv[nf];
    }
}

// ---------------------------------------------------------------- flash attention (R0 body; R10 adds slot->t remap only)
// CU c holds blocks {c, c+256, c+512} = slots {s, s+4, s+8}. Per-slot work
// (KV-tile units): t=0..7 -> 32-2t; t=8..11 (paired) -> 18. Identity map gives
// CU totals {74,70,66,62}; remap {0,1,2,3, 8,6,5,4, 9,10,11,7} balances every
// CU triple to exactly 68 ({32,18,18},{30,20,18},{28,22,18},{26,24,18}).
// Same work, same body — pure makespan balance. R5/R6 lessons: do not touch
// this kernel's sync structure or LDS footprint.
__global__ __launch_bounds__(256) void attn_kernel(
    const unsigned short* __restrict__ Q,    // (B*H, S, HD) rope'd * CS
    const unsigned short* __restrict__ Kg,   // (B*H, S, HD) rope'd
    const unsigned short* __restrict__ Vt,   // (B*H, HD, S)
    unsigned short* __restrict__ O) {        // (B, S, H, HD) bf16
  __shared__ unsigned short Ks[64 * 128];
  __shared__ unsigned short Vs[128 * 64];
  __shared__ unsigned short Ps[4 * 32 * 72];
  const int tid = threadIdx.x;
  const int lane = tid & 63, wv = tid >> 6;
  const int q15 = lane & 15, quad = lane >> 4;
  const int bh = blockIdx.x & 63;
  const int slot = blockIdx.x >> 6;          // 0..11
  // nibble-packed slot->t map: {0,1,2,3, 8,6,5,4, 9,10,11,7}
  const int t = (int)((0x7BA945683210ULL >> (slot * 4)) & 0xF);
  const int nseg = (t < 8) ? 1 : 2;
  const int b = bh >> 4, h = bh & 15;
  unsigned short* Pw = Ps + wv * (32 * 72);

  for (int seg = 0; seg < nseg; ++seg) {
    const int qt = (t < 8) ? (15 - t) : (seg == 0 ? (15 - t) : (t - 8));
    const int q0w = qt * 128 + wv * 32;

    bf16x8 qf[2][4];
#pragma unroll
    for (int nq = 0; nq < 2; ++nq) {
      const unsigned short* qp = Q + ((size_t)bh * SEQ + q0w + nq * 16 + q15) * HD + quad * 8;
#pragma unroll
      for (int ks = 0; ks < 4; ++ks) qf[nq][ks] = *(const bf16x8*)(qp + ks * 32);
    }

    f32x4 oacc[2][8] = {};
    float rs[2] = {0.f, 0.f};
    const int jmax = 2 * qt + 2;
    const int jcap = 2 * qt + (wv >> 1);

    for (int j = 0; j < jmax; ++j) {
      const int kv0 = j * 64;
      __syncthreads();
#pragma unroll
      for (int i = 0; i < 4; ++i) {
        int l = i * 256 + tid;
        int r = l >> 4, c = (l & 15) ^ (r & 15);
        async16(&Ks[l * 8], Kg + ((size_t)bh * SEQ + kv0 + r) * HD + c * 8);
      }
#pragma unroll
      for (int i = 0; i < 4; ++i) {
        int l = i * 256 + tid;
        int r = l >> 3, c = (l & 7) ^ (r & 7);
        async16(&Vs[l * 8], Vt + ((size_t)bh * HD + r) * SEQ + kv0 + c * 8);
      }
      __syncthreads();

      if (j <= jcap) {
        const bool edge = (j == jcap);
#pragma unroll
        for (int mi = 0; mi < 4; ++mi) {
          f32x4 st[2] = {};
#pragma unroll
          for (int ks = 0; ks < 4; ++ks) {
            int r = mi * 16 + q15;
            int c = ks * 4 + quad;
            bf16x8 kf = *(const bf16x8*)&Ks[(r * 16 + (c ^ (r & 15))) * 8];
#pragma unroll
            for (int nq = 0; nq < 2; ++nq)
              st[nq] = __builtin_amdgcn_mfma_f32_16x16x32_bf16(kf, qf[nq][ks], st[nq], 0, 0, 0);
          }
#pragma unroll
          for (int nq = 0; nq < 2; ++nq) {
            unsigned int u[4];
#pragma unroll
            for (int r = 0; r < 4; ++r) {
              float p = exp2f(st[nq][r]);
              if (edge) {
                int kv = kv0 + mi * 16 + quad * 4 + r;
                int qq = q0w + nq * 16 + q15;
                p = (kv > qq) ? 0.f : p;
              }
              unsigned int uu = __builtin_bit_cast(unsigned int, p) & 0xffff0000u;
              rs[nq] += __builtin_bit_cast(float, uu);
              u[r] = uu;
            }
            uint2 pk;
            pk.x = (u[0] >> 16) | u[1];
            pk.y = (u[2] >> 16) | u[3];
            *(uint2*)&Pw[(nq * 16 + q15) * 72 + mi * 16 + quad * 4] = pk;
          }
        }
#pragma unroll
        for (int ks = 0; ks < 2; ++ks) {
          bf16x8 pf[2];
#pragma unroll
          for (int mq = 0; mq < 2; ++mq)
            pf[mq] = *(const bf16x8*)&Pw[(mq * 16 + q15) * 72 + ks * 32 + quad * 8];
#pragma unroll
          for (int nf = 0; nf < 8; ++nf) {
            int r = nf * 16 + q15;
            int c = ks * 4 + quad;
            bf16x8 vf = *(const bf16x8*)&Vs[(r * 8 + (c ^ (r & 7))) * 8];
#pragma unroll
            for (int mq = 0; mq < 2; ++mq)
              oacc[mq][nf] = __builtin_amdgcn_mfma_f32_16x16x32_bf16(pf[mq], vf, oacc[mq][nf], 0, 0, 0);
          }
        }
      }
    }

    // segment epilogue: reduce row sums across quads, write O
#pragma unroll
    for (int nq = 0; nq < 2; ++nq) {
      rs[nq] += __shfl_xor(rs[nq], 16);
      rs[nq] += __shfl_xor(rs[nq], 32);
    }
#pragma unroll
    for (int mq = 0; mq < 2; ++mq) {
#pragma unroll
      for (int r = 0; r < 4; ++r) {
        float l = __shfl(rs[mq], quad * 4 + r);
        float inv = 1.0f / l;
        int qq = q0w + mq * 16 + quad * 4 + r;
        size_t base = (((size_t)b * SEQ + qq) * NH + h) * HD;
#pragma unroll
        for (int nf = 0; nf < 8; ++nf)
          O[base + nf * 16 + q15] = f2bf(oacc[mq][nf][r] * inv);
      }
    }
  }
}

// ---------------------------------------------------------------- launch
extern "C" void kernel_launch(void* const* d_in, const int* in_sizes, int n_in,
                              void* d_out, int out_size, void* d_ws, size_t ws_size,
                              hipStream_t stream) {
  (void)in_sizes; (void)n_in; (void)out_size; (void)ws_size;
  const float* x  = (const float*)d_in[0];
  const float* Wq = (const float*)d_in[1];
  const float* Wk = (const float*)d_in[2];
  const float* Wv = (const float*)d_in[3];
  const float* Wo = (const float*)d_in[4];
  const float* bo = (const float*)d_in[5];
  float* out = (float*)d_out;

  const size_t XE = (size_t)BATCH * SEQ * DIM;   // 16.7M elems
  const size_t WE = (size_t)DIM * DIM;           // 4.2M elems

  char* p = (char*)d_ws;
  unsigned short* xb   = (unsigned short*)p; p += XE * 2;
  unsigned short* Wall = (unsigned short*)p; p += 4 * WE * 2;
  unsigned short* Qg   = (unsigned short*)p; p += XE * 2;
  unsigned short* Kb   = (unsigned short*)p; p += XE * 2;
  unsigned short* Vtb  = (unsigned short*)p; p += XE * 2;
  unsigned short* attn = (unsigned short*)p; p += XE * 2;

  static bool attr_set = false;
  if (!attr_set) {
    hipFuncSetAttribute((const void*)gemm_out,
                        hipFuncAttributeMaxDynamicSharedMemorySize, 131072);
    attr_set = true;
  }

  cast_all_kernel<<<(int)(2 * XE / 4 / 256), 256, 0, stream>>>(x, Wq, Wk, Wv, Wo, xb);

  gemm_qkv<<<dim3(48, 64), 256, 0, stream>>>(
      xb, Wall, Wall + WE, Wall + 2 * WE, Qg, Kb, Vtb);

  attn_kernel<<<dim3(768), 256, 0, stream>>>(Qg, Kb, Vtb, attn);

  gemm_out<<<dim3(DIM / 256, (BATCH * SEQ) / 256), 512, 131072, stream>>>(
      attn, Wall + 3 * WE, out, bo);
}